// Round 5
// baseline (209.111 us; speedup 1.0000x reference)
//
#include <hip/hip_runtime.h>
#include <math.h>

#define TH 65536
#define SD 128
#define AD 8
#define HD 256

constexpr float GAMMA  = 0.99f;
constexpr float LMBDA  = 0.95f;
constexpr float EPSC   = 0.2f;
constexpr float VFC    = 0.5f;
constexpr float ENTC   = 0.01f;
constexpr float LOG2PI = 1.8378770664093453f;

typedef _Float16 half8 __attribute__((ext_vector_type(8)));
typedef __fp16 fp16x2 __attribute__((ext_vector_type(2)));
typedef __attribute__((ext_vector_type(4))) float f32x4;

// workspace layout (float offsets)
constexpr size_t WS_VALUES = 0;        // TH+1 (reserve 65540)
constexpr size_t WS_RATIO  = 131080;   // TH
constexpr size_t WS_CHP    = 196616;   // 64
constexpr size_t WS_CHB    = 196680;   // 64
constexpr size_t WS_SCAL   = 196744;   // 8: [0]sum [1]sumsq [2]vf [3]pg [4]ticket [5]ctrA [6]ctrB
constexpr size_t WS_BF     = 196752;   // f16 weights (ushort offsets below)
constexpr size_t SW_PIW1 = 0;          // 4*16*64*8  = 32768
constexpr size_t SW_PIW2 = 32768;      // 8*16*64*8  = 65536
constexpr size_t SW_VW1  = 98304;      // 32768
constexpr size_t SW_VW2  = 131072;     // 65536 -> total 196608 ushorts

__device__ __forceinline__ unsigned pk2h(float a, float b) {
    fp16x2 h = __builtin_amdgcn_cvt_pkrtz(a, b);
    return __builtin_bit_cast(unsigned, h);
}

// fast tanh: clamp + exp + hw rcp
__device__ __forceinline__ float ftanh(float x) {
    float cx = fminf(fmaxf(x, -9.f), 9.f);
    float e = __expf(cx + cx);
    return (e - 1.f) * __builtin_amdgcn_rcpf(e + 1.f);
}

// ------------- weight swizzle: coalesced f32 reads, scattered 2B f16 stores
// dest frag layout (read as half8 by MFMA B): frag = (ks*16 + nt)*64 + kq*16 + nr,
// elem j = k&7, where ks=k>>5, kq=(k>>3)&3, nt=n>>4, nr=n&15.
__global__ __launch_bounds__(256) void swizzle_kernel(
    const float* __restrict__ piW1, const float* __restrict__ vW1,
    const float* __restrict__ piW2, const float* __restrict__ vW2,
    unsigned short* __restrict__ dPiW1, unsigned short* __restrict__ dVW1,
    unsigned short* __restrict__ dPiW2, unsigned short* __restrict__ dVW2,
    float* __restrict__ scal)
{
    if (blockIdx.x == 0 && threadIdx.x < 8) scal[threadIdx.x] = 0.f;
    int g = blockIdx.x * 256 + threadIdx.x;   // float4 id, 49152 total
    const float* S; unsigned short* D; int lo;
    if      (g <  8192) { S = piW1; D = dPiW1; lo = 0;     }
    else if (g < 24576) { S = piW2; D = dPiW2; lo = 8192;  }
    else if (g < 32768) { S = vW1;  D = dVW1;  lo = 24576; }
    else                { S = vW2;  D = dVW2;  lo = 32768; }
    int q = g - lo;
    int k = q >> 6, n4 = (q & 63) * 4;        // 4 consecutive n, same nt
    float4 v = *(const float4*)(S + (size_t)k * HD + n4);
    int ks = k >> 5, kq = (k >> 3) & 3, j = k & 7;
    int nt = n4 >> 4, nr = n4 & 15;
    unsigned short* base = D + ((size_t)(ks * 16 + nt) * 64 + kq * 16 + nr) * 8 + j;
    unsigned p01 = pk2h(v.x, v.y);
    unsigned p23 = pk2h(v.z, v.w);
    base[0]  = (unsigned short)(p01 & 0xffff);
    base[8]  = (unsigned short)(p01 >> 16);
    base[16] = (unsigned short)(p23 & 0xffff);
    base[24] = (unsigned short)(p23 >> 16);
}

// one MLP layer for a 16x128 wave tile (8 col-tiles), A from LDS, B from global
template <int NKS, int ASTRIDE>
__device__ __forceinline__ void runlayer(
    f32x4* acc, const unsigned short* __restrict__ Ws,
    const unsigned short* ab, int l15, int quad, int rowgrp, int colhalf, int lane)
{
#pragma unroll
    for (int nt = 0; nt < 8; ++nt) acc[nt] = (f32x4){0.f, 0.f, 0.f, 0.f};
#pragma unroll
    for (int ks = 0; ks < NKS; ++ks) {
        half8 af = *(const half8*)(ab + (rowgrp * 16 + l15) * ASTRIDE + ks * 32 + quad * 8);
#pragma unroll
        for (int ntl = 0; ntl < 8; ++ntl) {
            half8 bf = ((const half8*)Ws)[(ks * 16 + colhalf * 8 + ntl) * 64 + lane];
            acc[ntl] = __builtin_amdgcn_mfma_f32_16x16x32_f16(af, bf, acc[ntl], 0, 0, 0);
        }
    }
}

// store 4 row-consecutive tanh outputs into LDS f16 (pk convert, 2 inst / 4 vals)
__device__ __forceinline__ void store4(unsigned short* dst, int stride,
                                       float t0, float t1, float t2, float t3)
{
    unsigned p01 = pk2h(t0, t1), p23 = pk2h(t2, t3);
    dst[0]          = (unsigned short)(p01 & 0xffff);
    dst[stride]     = (unsigned short)(p01 >> 16);
    dst[2 * stride] = (unsigned short)(p23 & 0xffff);
    dst[3 * stride] = (unsigned short)(p23 >> 16);
}

// ------------- fused pi+v MLP: per 32-row tile computes ratio[] (pi) and values[] (v)
__global__ __launch_bounds__(256, 3) void mlp_fused_kernel(
    const float* __restrict__ X, const float* __restrict__ Xlast,
    const unsigned short* __restrict__ piW1s, const float* __restrict__ pib1,
    const unsigned short* __restrict__ piW2s, const float* __restrict__ pib2,
    const float* __restrict__ muW, const float* __restrict__ mub,
    const float* __restrict__ logstd,
    const float* __restrict__ act, const float* __restrict__ lpold,
    const unsigned short* __restrict__ vW1s, const float* __restrict__ vb1,
    const unsigned short* __restrict__ vW2s, const float* __restrict__ vb2,
    const float* __restrict__ vhW, const float* __restrict__ vhb,
    float* __restrict__ values, float* __restrict__ ratio)
{
    __shared__ unsigned short xs[32 * 136];   // 8704 B
    __shared__ unsigned short h1[32 * 264];   // 16896 B
    __shared__ float cmb[2][32][8];           // 2048 B
    const int tid = threadIdx.x;
    const int lane = tid & 63, wave = tid >> 6;
    const int l15 = lane & 15, quad = lane >> 4;
    const int rowgrp = wave >> 1, colhalf = wave & 1;
    const bool vonly = (blockIdx.x == gridDim.x - 1);
    const float* Xp = vonly ? Xlast : X + (size_t)blockIdx.x * 32 * SD;
    const int nrows = vonly ? 1 : 32;
    const int vout0 = vonly ? TH : blockIdx.x * 32;

    // stage 32x128 f32 -> f16 LDS (row stride 136 ushorts)
#pragma unroll
    for (int i = 0; i < 4; ++i) {
        int f = tid + i * 256;
        int rr = f >> 5, c4 = f & 31;
        float4 v = make_float4(0.f, 0.f, 0.f, 0.f);
        if (rr < nrows) v = *(const float4*)(Xp + (size_t)rr * SD + c4 * 4);
        *(uint2*)(xs + rr * 136 + c4 * 4) = make_uint2(pk2h(v.x, v.y), pk2h(v.z, v.w));
    }
    __syncthreads();

    f32x4 acc[8];

    if (!vonly) {
        // ---- pi layer 1
        runlayer<4, 136>(acc, piW1s, xs, l15, quad, rowgrp, colhalf, lane);
#pragma unroll
        for (int ntl = 0; ntl < 8; ++ntl) {
            int col = (colhalf * 8 + ntl) * 16 + l15;
            float bb = pib1[col];
            store4(&h1[(rowgrp * 16 + quad * 4) * 264 + col], 264,
                   ftanh(acc[ntl][0] + bb), ftanh(acc[ntl][1] + bb),
                   ftanh(acc[ntl][2] + bb), ftanh(acc[ntl][3] + bb));
        }
        __syncthreads();
        // ---- pi layer 2
        runlayer<8, 264>(acc, piW2s, h1, l15, quad, rowgrp, colhalf, lane);
        // ---- mu head partials (fp32 VALU dot over this wave's 8 cols)
        float pm[4][8];
#pragma unroll
        for (int rg = 0; rg < 4; ++rg)
#pragma unroll
            for (int aj = 0; aj < 8; ++aj) pm[rg][aj] = 0.f;
#pragma unroll
        for (int ntl = 0; ntl < 8; ++ntl) {
            int col = (colhalf * 8 + ntl) * 16 + l15;
            float bb = pib2[col];
            float4 w0 = *(const float4*)(muW + (size_t)col * AD);
            float4 w1 = *(const float4*)(muW + (size_t)col * AD + 4);
            float wv[8] = {w0.x, w0.y, w0.z, w0.w, w1.x, w1.y, w1.z, w1.w};
#pragma unroll
            for (int rg = 0; rg < 4; ++rg) {
                float hv = ftanh(acc[ntl][rg] + bb);
#pragma unroll
                for (int aj = 0; aj < 8; ++aj) pm[rg][aj] = fmaf(hv, wv[aj], pm[rg][aj]);
            }
        }
#pragma unroll
        for (int off = 8; off >= 1; off >>= 1)
#pragma unroll
            for (int rg = 0; rg < 4; ++rg)
#pragma unroll
                for (int aj = 0; aj < 8; ++aj)
                    pm[rg][aj] += __shfl_xor(pm[rg][aj], off, 16);
        if (l15 == 0) {
#pragma unroll
            for (int rg = 0; rg < 4; ++rg) {
                *(float4*)&cmb[colhalf][rowgrp * 16 + quad * 4 + rg][0] =
                    make_float4(pm[rg][0], pm[rg][1], pm[rg][2], pm[rg][3]);
                *(float4*)&cmb[colhalf][rowgrp * 16 + quad * 4 + rg][4] =
                    make_float4(pm[rg][4], pm[rg][5], pm[rg][6], pm[rg][7]);
            }
        }
        __syncthreads();
        // ---- per-row log-prob ratio
        if (tid < 32) {
            int row = blockIdx.x * 32 + tid;
            const float* ar = act + (size_t)row * AD;
            float lp = 0.f;
#pragma unroll
            for (int aj = 0; aj < 8; ++aj) {
                float ls = logstd[aj];
                float mu = cmb[0][tid][aj] + cmb[1][tid][aj] + mub[aj];
                float z = (ar[aj] - mu) * __expf(-ls);
                lp += -0.5f * z * z - ls;
            }
            lp -= 4.f * LOG2PI;
            ratio[row] = __expf(lp - lpold[row]);
        }
    }

    // ---- v layer 1 (reads xs; h1 reads of pi layer2 were barrier-ordered above)
    runlayer<4, 136>(acc, vW1s, xs, l15, quad, rowgrp, colhalf, lane);
#pragma unroll
    for (int ntl = 0; ntl < 8; ++ntl) {
        int col = (colhalf * 8 + ntl) * 16 + l15;
        float bb = vb1[col];
        store4(&h1[(rowgrp * 16 + quad * 4) * 264 + col], 264,
               ftanh(acc[ntl][0] + bb), ftanh(acc[ntl][1] + bb),
               ftanh(acc[ntl][2] + bb), ftanh(acc[ntl][3] + bb));
    }
    __syncthreads();
    // ---- v layer 2 + value head
    runlayer<8, 264>(acc, vW2s, h1, l15, quad, rowgrp, colhalf, lane);
    float vp[4] = {0.f, 0.f, 0.f, 0.f};
#pragma unroll
    for (int ntl = 0; ntl < 8; ++ntl) {
        int col = (colhalf * 8 + ntl) * 16 + l15;
        float bb = vb2[col], w = vhW[col];
#pragma unroll
        for (int rg = 0; rg < 4; ++rg) vp[rg] += ftanh(acc[ntl][rg] + bb) * w;
    }
#pragma unroll
    for (int off = 8; off >= 1; off >>= 1)
#pragma unroll
        for (int rg = 0; rg < 4; ++rg) vp[rg] += __shfl_xor(vp[rg], off, 16);
    if (l15 == 0) {
#pragma unroll
        for (int rg = 0; rg < 4; ++rg)
            cmb[colhalf][rowgrp * 16 + quad * 4 + rg][0] = vp[rg];
    }
    __syncthreads();
    if (tid < nrows)
        values[vout0 + tid] = cmb[0][tid][0] + cmb[1][tid][0] + vhb[0];
}

// ------------- single fused GAE + PG kernel (64 co-resident blocks, atomic phases)
__global__ __launch_bounds__(256) void gae_fused_kernel(
    const float* __restrict__ rw, const float* __restrict__ m,
    const float* __restrict__ values, const float* __restrict__ ratio,
    const float* __restrict__ logstd,
    float* __restrict__ chunkP, float* __restrict__ chunkB,
    float* __restrict__ scal, float* __restrict__ out)
{
    __shared__ float sp_[256], sb_[256];
    __shared__ float cp[64], cb[64];
    __shared__ float red[12];
    __shared__ float bcast[4];
    const int j = threadIdx.x;
    const int t0 = blockIdx.x * 1024 + j * 4;
    const float g = GAMMA * LMBDA;

    // --- phase A: local deltas + block suffix scan of affine maps
    float4 vv = *(const float4*)(values + t0);
    float v4 = values[t0 + 4];
    float4 rr = *(const float4*)(rw + t0);
    float4 mm = *(const float4*)(m + t0);
    float vs[5] = {vv.x, vv.y, vv.z, vv.w, v4};
    float rs[4] = {rr.x, rr.y, rr.z, rr.w};
    float ms[4] = {mm.x, mm.y, mm.z, mm.w};
    float ds[4];
#pragma unroll
    for (int i = 0; i < 4; ++i)
        ds[i] = rs[i] + GAMMA * vs[i + 1] * ms[i] - vs[i];

    float P = 1.f, B = 0.f;
#pragma unroll
    for (int i = 3; i >= 0; --i) {
        float p = g * ms[i];
        B = ds[i] + p * B;
        P = p * P;
    }
    sp_[j] = P; sb_[j] = B;
    __syncthreads();
    for (int dstep = 1; dstep < 256; dstep <<= 1) {
        float pj = sp_[j], bj = sb_[j], pk = 1.f, bk = 0.f;
        if (j + dstep < 256) { pk = sp_[j + dstep]; bk = sb_[j + dstep]; }
        __syncthreads();
        sp_[j] = pj * pk;
        sb_[j] = bj + pj * bk;
        __syncthreads();
    }
    if (j == 0) {
        atomicExch(&chunkP[blockIdx.x], sp_[0]);
        atomicExch(&chunkB[blockIdx.x], sb_[0]);
        __threadfence();
        atomicAdd(&scal[5], 1.f);
        // spin until all 64 chunks published
        while (atomicAdd(&scal[5], 0.f) < 64.f) __builtin_amdgcn_s_sleep(2);
    }
    __syncthreads();
    // --- phase B: parallel fetch of all chunk (P,B), serial compose in LDS
    if (j < 64) {
        cp[j] = atomicAdd(&chunkP[j], 0.f);
        cb[j] = atomicAdd(&chunkB[j], 0.f);
    }
    __syncthreads();
    if (j == 0) {
        float A = 0.f;
        for (int c = 63; c > (int)blockIdx.x; --c) A = cb[c] + cp[c] * A;
        bcast[0] = A;
    }
    __syncthreads();
    const float carry = bcast[0];

    // --- phase C: apply carry, advantages in regs, sum/sumsq/huber reductions
    float Pe = 1.f, Be = 0.f;
    if (j < 255) { Pe = sp_[j + 1]; Be = sb_[j + 1]; }
    float A = Be + Pe * carry;
    float s1 = 0.f, s2 = 0.f, vf = 0.f;
    float a4[4];
#pragma unroll
    for (int i = 3; i >= 0; --i) {
        A = ds[i] + g * ms[i] * A;
        a4[i] = A;
        float ab = fabsf(A);
        vf += (ab < 1.f) ? 0.5f * A * A : ab - 0.5f;   // huber(v-ret) == huber(adv)
        s1 += A;
        s2 += A * A;
    }
#pragma unroll
    for (int off = 32; off >= 1; off >>= 1) {
        s1 += __shfl_down(s1, off, 64);
        s2 += __shfl_down(s2, off, 64);
        vf += __shfl_down(vf, off, 64);
    }
    if ((j & 63) == 0) {
        int w = j >> 6;
        red[w] = s1; red[4 + w] = s2; red[8 + w] = vf;
    }
    __syncthreads();
    if (j == 0) {
        atomicAdd(&scal[0], red[0] + red[1] + red[2] + red[3]);
        atomicAdd(&scal[1], red[4] + red[5] + red[6] + red[7]);
        atomicAdd(&scal[2], red[8] + red[9] + red[10] + red[11]);
        __threadfence();
        atomicAdd(&scal[6], 1.f);
        while (atomicAdd(&scal[6], 0.f) < 64.f) __builtin_amdgcn_s_sleep(2);
        bcast[1] = atomicAdd(&scal[0], 0.f);
        bcast[2] = atomicAdd(&scal[1], 0.f);
    }
    __syncthreads();

    // --- phase D: normalize + clipped PG over in-register advantages
    const float ssum = bcast[1], ssq = bcast[2];
    const float meanA = ssum / (float)TH;
    const float varA = fmaxf((ssq - ssum * ssum / (float)TH) / (float)(TH - 1), 0.f);
    const float inv = 1.f / (sqrtf(varA) + 1e-8f);

    float4 r4 = *(const float4*)(ratio + t0);
    float rt[4] = {r4.x, r4.y, r4.z, r4.w};
    float pg = 0.f;
#pragma unroll
    for (int i = 0; i < 4; ++i) {
        float aN = (a4[i] - meanA) * inv;
        float rc = fminf(fmaxf(rt[i], 1.f - EPSC), 1.f + EPSC);
        pg -= fminf(rt[i] * aN, rc * aN);
    }
#pragma unroll
    for (int off = 32; off >= 1; off >>= 1) pg += __shfl_down(pg, off, 64);
    if ((j & 63) == 0) red[j >> 6] = pg;
    __syncthreads();
    if (j == 0) {
        atomicAdd(&scal[3], red[0] + red[1] + red[2] + red[3]);
        __threadfence();
        float old = atomicAdd(&scal[4], 1.f);
        if (old == 63.f) {   // last block: all pg partials visible
            float pgs = atomicAdd(&scal[3], 0.f);
            float vfs = atomicAdd(&scal[2], 0.f);
            float ls = 0.f;
#pragma unroll
            for (int jj = 0; jj < AD; ++jj) ls += logstd[jj];
            float entropy = 0.5f + 0.5f * LOG2PI + ls / (float)AD;
            out[0] = pgs / (float)TH + VFC * (vfs / (float)TH) - ENTC * entropy;
        }
    }
}

extern "C" void kernel_launch(void* const* d_in, const int* in_sizes, int n_in,
                              void* d_out, int out_size, void* d_ws, size_t ws_size,
                              hipStream_t stream) {
    const float* s      = (const float*)d_in[0];
    const float* a      = (const float*)d_in[1];
    const float* r      = (const float*)d_in[2];
    const float* sp     = (const float*)d_in[3];
    const float* lpold  = (const float*)d_in[4];
    const float* dmask  = (const float*)d_in[5];
    const float* piW1   = (const float*)d_in[6];
    const float* pib1   = (const float*)d_in[7];
    const float* piW2   = (const float*)d_in[8];
    const float* pib2   = (const float*)d_in[9];
    const float* muW    = (const float*)d_in[10];
    const float* mub    = (const float*)d_in[11];
    const float* logstd = (const float*)d_in[12];
    const float* vW1    = (const float*)d_in[13];
    const float* vb1    = (const float*)d_in[14];
    const float* vW2    = (const float*)d_in[15];
    const float* vb2    = (const float*)d_in[16];
    const float* vhW    = (const float*)d_in[17];
    const float* vhb    = (const float*)d_in[18];

    float* ws      = (float*)d_ws;
    float* values  = ws + WS_VALUES;
    float* ratio   = ws + WS_RATIO;
    float* chunkP  = ws + WS_CHP;
    float* chunkB  = ws + WS_CHB;
    float* scal    = ws + WS_SCAL;
    unsigned short* bfbase = (unsigned short*)(ws + WS_BF);
    unsigned short* dPiW1 = bfbase + SW_PIW1;
    unsigned short* dPiW2 = bfbase + SW_PIW2;
    unsigned short* dVW1  = bfbase + SW_VW1;
    unsigned short* dVW2  = bfbase + SW_VW2;

    swizzle_kernel<<<192, 256, 0, stream>>>(piW1, vW1, piW2, vW2,
                                            dPiW1, dVW1, dPiW2, dVW2, scal);

    mlp_fused_kernel<<<TH / 32 + 1, 256, 0, stream>>>(
        s, sp + (size_t)(TH - 1) * SD,
        dPiW1, pib1, dPiW2, pib2, muW, mub, logstd, a, lpold,
        dVW1, vb1, dVW2, vb2, vhW, vhb,
        values, ratio);

    gae_fused_kernel<<<64, 256, 0, stream>>>(r, dmask, values, ratio, logstd,
                                             chunkP, chunkB, scal, (float*)d_out);
}

// Round 7
// 184.973 us; speedup vs baseline: 1.1305x; 1.1305x over previous
//
#include <hip/hip_runtime.h>
#include <math.h>

#define TH 65536
#define SD 128
#define AD 8
#define HD 256

constexpr float GAMMA  = 0.99f;
constexpr float LMBDA  = 0.95f;
constexpr float EPSC   = 0.2f;
constexpr float VFC    = 0.5f;
constexpr float ENTC   = 0.01f;
constexpr float LOG2PI = 1.8378770664093453f;

typedef _Float16 half8 __attribute__((ext_vector_type(8)));
typedef __fp16 fp16x2 __attribute__((ext_vector_type(2)));
typedef __attribute__((ext_vector_type(4))) float f32x4;

// workspace layout (float offsets)
constexpr size_t WS_VALUES = 0;        // TH+1 (reserve 65540)
constexpr size_t WS_RATIO  = 131080;   // TH
constexpr size_t WS_CHP    = 196616;   // 64
constexpr size_t WS_CHB    = 196680;   // 64
constexpr size_t WS_SCAL   = 196744;   // 8: [0]sum [1]sumsq [2]vf [3]pg [4]ticket [5]ctrA [6]ctrB
constexpr size_t WS_BF     = 196752;   // f16 weights (ushort offsets below)
constexpr size_t SW_PIW1 = 0;          // 32768
constexpr size_t SW_PIW2 = 32768;      // 65536
constexpr size_t SW_VW1  = 98304;      // 32768
constexpr size_t SW_VW2  = 131072;     // 65536 -> total 196608 ushorts

__device__ __forceinline__ unsigned pk2h(float a, float b) {
    fp16x2 h = __builtin_amdgcn_cvt_pkrtz(a, b);
    return __builtin_bit_cast(unsigned, h);
}

// fast tanh: clamp + exp + hw rcp
__device__ __forceinline__ float ftanh(float x) {
    float cx = fminf(fmaxf(x, -9.f), 9.f);
    float e = __expf(cx + cx);
    return (e - 1.f) * __builtin_amdgcn_rcpf(e + 1.f);
}

// ------------- weight swizzle: coalesced f32 reads, scattered 2B f16 stores
// dest frag layout (read as half8 by MFMA B): frag = (ks*16 + nt)*64 + kq*16 + nr,
// elem j = k&7, where ks=k>>5, kq=(k>>3)&3, nt=n>>4, nr=n&15.
__global__ __launch_bounds__(256) void swizzle_kernel(
    const float* __restrict__ piW1, const float* __restrict__ vW1,
    const float* __restrict__ piW2, const float* __restrict__ vW2,
    unsigned short* __restrict__ dPiW1, unsigned short* __restrict__ dVW1,
    unsigned short* __restrict__ dPiW2, unsigned short* __restrict__ dVW2,
    float* __restrict__ scal)
{
    if (blockIdx.x == 0 && threadIdx.x < 8) scal[threadIdx.x] = 0.f;
    int g = blockIdx.x * 256 + threadIdx.x;   // float4 id, 49152 total
    const float* S; unsigned short* D; int lo;
    if      (g <  8192) { S = piW1; D = dPiW1; lo = 0;     }
    else if (g < 24576) { S = piW2; D = dPiW2; lo = 8192;  }
    else if (g < 32768) { S = vW1;  D = dVW1;  lo = 24576; }
    else                { S = vW2;  D = dVW2;  lo = 32768; }
    int q = g - lo;
    int k = q >> 6, n4 = (q & 63) * 4;        // 4 consecutive n, same nt
    float4 v = *(const float4*)(S + (size_t)k * HD + n4);
    int ks = k >> 5, kq = (k >> 3) & 3, j = k & 7;
    int nt = n4 >> 4, nr = n4 & 15;
    unsigned short* base = D + ((size_t)(ks * 16 + nt) * 64 + kq * 16 + nr) * 8 + j;
    unsigned p01 = pk2h(v.x, v.y);
    unsigned p23 = pk2h(v.z, v.w);
    base[0]  = (unsigned short)(p01 & 0xffff);
    base[8]  = (unsigned short)(p01 >> 16);
    base[16] = (unsigned short)(p23 & 0xffff);
    base[24] = (unsigned short)(p23 >> 16);
}

// one MLP layer for a 16x128 wave tile (8 col-tiles), A from LDS, B from global
template <int NKS, int ASTRIDE>
__device__ __forceinline__ void runlayer(
    f32x4* acc, const unsigned short* __restrict__ Ws,
    const unsigned short* ab, int l15, int quad, int rowgrp, int colhalf, int lane)
{
#pragma unroll
    for (int nt = 0; nt < 8; ++nt) acc[nt] = (f32x4){0.f, 0.f, 0.f, 0.f};
#pragma unroll
    for (int ks = 0; ks < NKS; ++ks) {
        half8 af = *(const half8*)(ab + (rowgrp * 16 + l15) * ASTRIDE + ks * 32 + quad * 8);
#pragma unroll
        for (int ntl = 0; ntl < 8; ++ntl) {
            half8 bf = ((const half8*)Ws)[(ks * 16 + colhalf * 8 + ntl) * 64 + lane];
            acc[ntl] = __builtin_amdgcn_mfma_f32_16x16x32_f16(af, bf, acc[ntl], 0, 0, 0);
        }
    }
}

// store 4 row-consecutive tanh outputs into LDS f16 (pk convert)
__device__ __forceinline__ void store4(unsigned short* dst, int stride,
                                       float t0, float t1, float t2, float t3)
{
    unsigned p01 = pk2h(t0, t1), p23 = pk2h(t2, t3);
    dst[0]          = (unsigned short)(p01 & 0xffff);
    dst[stride]     = (unsigned short)(p01 >> 16);
    dst[2 * stride] = (unsigned short)(p23 & 0xffff);
    dst[3 * stride] = (unsigned short)(p23 >> 16);
}

// ------------- fused pi+v MLP on TRUE 64-row tiles (4 rowgroups x 2 colhalves)
__global__ __launch_bounds__(256, 3) void mlp_fused_kernel(
    const float* __restrict__ X, const float* __restrict__ Xlast,
    const unsigned short* __restrict__ piW1s, const float* __restrict__ pib1,
    const unsigned short* __restrict__ piW2s, const float* __restrict__ pib2,
    const float* __restrict__ muW, const float* __restrict__ mub,
    const float* __restrict__ logstd,
    const float* __restrict__ act, const float* __restrict__ lpold,
    const unsigned short* __restrict__ vW1s, const float* __restrict__ vb1,
    const unsigned short* __restrict__ vW2s, const float* __restrict__ vb2,
    const float* __restrict__ vhW, const float* __restrict__ vhb,
    float* __restrict__ values, float* __restrict__ ratio)
{
    __shared__ unsigned short xs[64 * 136];   // 17408 B
    __shared__ unsigned short h1[64 * 264];   // 33792 B
    __shared__ float cmb[64 * 8];             // 2048 B: mu accumulators (atomicAdd)
    __shared__ float val[64];                 // 256 B: value partial accumulators
    const int tid = threadIdx.x;
    const int lane = tid & 63, wave = tid >> 6;
    const int l15 = lane & 15, quad = lane >> 4;
    const int rowgrp = wave >> 1, colhalf = wave & 1;   // 4 x 2 over 64 rows
    const bool vonly = (blockIdx.x == gridDim.x - 1);
    const float* Xp = vonly ? Xlast : X + (size_t)blockIdx.x * 64 * SD;
    const int nrows = vonly ? 1 : 64;
    const int vout0 = vonly ? TH : blockIdx.x * 64;

    // zero the LDS accumulators (ws is poisoned each launch)
    if (tid < 64) val[tid] = 0.f;
    cmb[tid] = 0.f; cmb[tid + 256] = 0.f;

    // stage 64x128 f32 -> f16 LDS (row stride 136 ushorts)
#pragma unroll
    for (int i = 0; i < 8; ++i) {
        int f = tid + i * 256;
        int rr = f >> 5, c4 = f & 31;
        float4 v = make_float4(0.f, 0.f, 0.f, 0.f);
        if (rr < nrows) v = *(const float4*)(Xp + (size_t)rr * SD + c4 * 4);
        *(uint2*)(xs + rr * 136 + c4 * 4) = make_uint2(pk2h(v.x, v.y), pk2h(v.z, v.w));
    }
    __syncthreads();

    f32x4 acc[8];

    if (!vonly) {
        // ---- pi layer 1
        runlayer<4, 136>(acc, piW1s, xs, l15, quad, rowgrp, colhalf, lane);
#pragma unroll
        for (int ntl = 0; ntl < 8; ++ntl) {
            int col = (colhalf * 8 + ntl) * 16 + l15;
            float bb = pib1[col];
            store4(&h1[(rowgrp * 16 + quad * 4) * 264 + col], 264,
                   ftanh(acc[ntl][0] + bb), ftanh(acc[ntl][1] + bb),
                   ftanh(acc[ntl][2] + bb), ftanh(acc[ntl][3] + bb));
        }
        __syncthreads();
        // ---- pi layer 2
        runlayer<8, 264>(acc, piW2s, h1, l15, quad, rowgrp, colhalf, lane);
        // ---- mu head partials (fp32 VALU dot over this wave's 128 cols)
        float pm[4][8];
#pragma unroll
        for (int rg = 0; rg < 4; ++rg)
#pragma unroll
            for (int aj = 0; aj < 8; ++aj) pm[rg][aj] = 0.f;
#pragma unroll
        for (int ntl = 0; ntl < 8; ++ntl) {
            int col = (colhalf * 8 + ntl) * 16 + l15;
            float bb = pib2[col];
            float4 w0 = *(const float4*)(muW + (size_t)col * AD);
            float4 w1 = *(const float4*)(muW + (size_t)col * AD + 4);
            float wv[8] = {w0.x, w0.y, w0.z, w0.w, w1.x, w1.y, w1.z, w1.w};
#pragma unroll
            for (int rg = 0; rg < 4; ++rg) {
                float hv = ftanh(acc[ntl][rg] + bb);
#pragma unroll
                for (int aj = 0; aj < 8; ++aj) pm[rg][aj] = fmaf(hv, wv[aj], pm[rg][aj]);
            }
        }
#pragma unroll
        for (int off = 8; off >= 1; off >>= 1)
#pragma unroll
            for (int rg = 0; rg < 4; ++rg)
#pragma unroll
                for (int aj = 0; aj < 8; ++aj)
                    pm[rg][aj] += __shfl_xor(pm[rg][aj], off, 16);
        if (l15 == 0) {
#pragma unroll
            for (int rg = 0; rg < 4; ++rg) {
                int rowi = rowgrp * 16 + quad * 4 + rg;
#pragma unroll
                for (int aj = 0; aj < 8; ++aj)
                    atomicAdd(&cmb[rowi * 8 + aj], pm[rg][aj]);
            }
        }
        __syncthreads();
        // ---- per-row log-prob ratio (reads cmb only)
        if (tid < 64) {
            int row = blockIdx.x * 64 + tid;
            const float* ar = act + (size_t)row * AD;
            float lp = 0.f;
#pragma unroll
            for (int aj = 0; aj < 8; ++aj) {
                float ls = logstd[aj];
                float mu = cmb[tid * 8 + aj] + mub[aj];
                float z = (ar[aj] - mu) * __expf(-ls);
                lp += -0.5f * z * z - ls;
            }
            lp -= 4.f * LOG2PI;
            ratio[row] = __expf(lp - lpold[row]);
        }
    }

    // ---- v layer 1 (reads xs; h1 reads of pi layer2 were barrier-ordered above)
    runlayer<4, 136>(acc, vW1s, xs, l15, quad, rowgrp, colhalf, lane);
#pragma unroll
    for (int ntl = 0; ntl < 8; ++ntl) {
        int col = (colhalf * 8 + ntl) * 16 + l15;
        float bb = vb1[col];
        store4(&h1[(rowgrp * 16 + quad * 4) * 264 + col], 264,
               ftanh(acc[ntl][0] + bb), ftanh(acc[ntl][1] + bb),
               ftanh(acc[ntl][2] + bb), ftanh(acc[ntl][3] + bb));
    }
    __syncthreads();
    // ---- v layer 2 + value head
    runlayer<8, 264>(acc, vW2s, h1, l15, quad, rowgrp, colhalf, lane);
    float vp[4] = {0.f, 0.f, 0.f, 0.f};
#pragma unroll
    for (int ntl = 0; ntl < 8; ++ntl) {
        int col = (colhalf * 8 + ntl) * 16 + l15;
        float bb = vb2[col], w = vhW[col];
#pragma unroll
        for (int rg = 0; rg < 4; ++rg) vp[rg] += ftanh(acc[ntl][rg] + bb) * w;
    }
#pragma unroll
    for (int off = 8; off >= 1; off >>= 1)
#pragma unroll
        for (int rg = 0; rg < 4; ++rg) vp[rg] += __shfl_xor(vp[rg], off, 16);
    if (l15 == 0) {
#pragma unroll
        for (int rg = 0; rg < 4; ++rg)
            atomicAdd(&val[rowgrp * 16 + quad * 4 + rg], vp[rg]);
    }
    __syncthreads();
    if (tid < nrows)
        values[vout0 + tid] = val[tid] + vhb[0];
}

// ------------- single fused GAE + PG kernel (64 co-resident blocks, atomic phases)
__global__ __launch_bounds__(256) void gae_fused_kernel(
    const float* __restrict__ rw, const float* __restrict__ m,
    const float* __restrict__ values, const float* __restrict__ ratio,
    const float* __restrict__ logstd,
    float* __restrict__ chunkP, float* __restrict__ chunkB,
    float* __restrict__ scal, float* __restrict__ out)
{
    __shared__ float sp_[256], sb_[256];
    __shared__ float cp[64], cb[64];
    __shared__ float red[12];
    __shared__ float bcast[4];
    const int j = threadIdx.x;
    const int t0 = blockIdx.x * 1024 + j * 4;
    const float g = GAMMA * LMBDA;

    // --- phase A: local deltas + block suffix scan of affine maps
    float4 vv = *(const float4*)(values + t0);
    float v4 = values[t0 + 4];
    float4 rr = *(const float4*)(rw + t0);
    float4 mm = *(const float4*)(m + t0);
    float vs[5] = {vv.x, vv.y, vv.z, vv.w, v4};
    float rs[4] = {rr.x, rr.y, rr.z, rr.w};
    float ms[4] = {mm.x, mm.y, mm.z, mm.w};
    float ds[4];
#pragma unroll
    for (int i = 0; i < 4; ++i)
        ds[i] = rs[i] + GAMMA * vs[i + 1] * ms[i] - vs[i];

    float P = 1.f, B = 0.f;
#pragma unroll
    for (int i = 3; i >= 0; --i) {
        float p = g * ms[i];
        B = ds[i] + p * B;
        P = p * P;
    }
    sp_[j] = P; sb_[j] = B;
    __syncthreads();
    for (int dstep = 1; dstep < 256; dstep <<= 1) {
        float pj = sp_[j], bj = sb_[j], pk = 1.f, bk = 0.f;
        if (j + dstep < 256) { pk = sp_[j + dstep]; bk = sb_[j + dstep]; }
        __syncthreads();
        sp_[j] = pj * pk;
        sb_[j] = bj + pj * bk;
        __syncthreads();
    }
    if (j == 0) {
        atomicExch(&chunkP[blockIdx.x], sp_[0]);
        atomicExch(&chunkB[blockIdx.x], sb_[0]);
        __threadfence();
        atomicAdd(&scal[5], 1.f);
        while (atomicAdd(&scal[5], 0.f) < 64.f) __builtin_amdgcn_s_sleep(2);
    }
    __syncthreads();
    // --- phase B: parallel fetch of all chunk (P,B), serial compose in LDS
    if (j < 64) {
        cp[j] = atomicAdd(&chunkP[j], 0.f);
        cb[j] = atomicAdd(&chunkB[j], 0.f);
    }
    __syncthreads();
    if (j == 0) {
        float A = 0.f;
        for (int c = 63; c > (int)blockIdx.x; --c) A = cb[c] + cp[c] * A;
        bcast[0] = A;
    }
    __syncthreads();
    const float carry = bcast[0];

    // --- phase C: apply carry, advantages in regs, sum/sumsq/huber reductions
    float Pe = 1.f, Be = 0.f;
    if (j < 255) { Pe = sp_[j + 1]; Be = sb_[j + 1]; }
    float A = Be + Pe * carry;
    float s1 = 0.f, s2 = 0.f, vf = 0.f;
    float a4[4];
#pragma unroll
    for (int i = 3; i >= 0; --i) {
        A = ds[i] + g * ms[i] * A;
        a4[i] = A;
        float ab = fabsf(A);
        vf += (ab < 1.f) ? 0.5f * A * A : ab - 0.5f;   // huber(v-ret) == huber(adv)
        s1 += A;
        s2 += A * A;
    }
#pragma unroll
    for (int off = 32; off >= 1; off >>= 1) {
        s1 += __shfl_down(s1, off, 64);
        s2 += __shfl_down(s2, off, 64);
        vf += __shfl_down(vf, off, 64);
    }
    if ((j & 63) == 0) {
        int w = j >> 6;
        red[w] = s1; red[4 + w] = s2; red[8 + w] = vf;
    }
    __syncthreads();
    if (j == 0) {
        atomicAdd(&scal[0], red[0] + red[1] + red[2] + red[3]);
        atomicAdd(&scal[1], red[4] + red[5] + red[6] + red[7]);
        atomicAdd(&scal[2], red[8] + red[9] + red[10] + red[11]);
        __threadfence();
        atomicAdd(&scal[6], 1.f);
        while (atomicAdd(&scal[6], 0.f) < 64.f) __builtin_amdgcn_s_sleep(2);
        bcast[1] = atomicAdd(&scal[0], 0.f);
        bcast[2] = atomicAdd(&scal[1], 0.f);
    }
    __syncthreads();

    // --- phase D: normalize + clipped PG over in-register advantages
    const float ssum = bcast[1], ssq = bcast[2];
    const float meanA = ssum / (float)TH;
    const float varA = fmaxf((ssq - ssum * ssum / (float)TH) / (float)(TH - 1), 0.f);
    const float inv = 1.f / (sqrtf(varA) + 1e-8f);

    float4 r4 = *(const float4*)(ratio + t0);
    float rt[4] = {r4.x, r4.y, r4.z, r4.w};
    float pg = 0.f;
#pragma unroll
    for (int i = 0; i < 4; ++i) {
        float aN = (a4[i] - meanA) * inv;
        float rc = fminf(fmaxf(rt[i], 1.f - EPSC), 1.f + EPSC);
        pg -= fminf(rt[i] * aN, rc * aN);
    }
#pragma unroll
    for (int off = 32; off >= 1; off >>= 1) pg += __shfl_down(pg, off, 64);
    if ((j & 63) == 0) red[j >> 6] = pg;
    __syncthreads();
    if (j == 0) {
        atomicAdd(&scal[3], red[0] + red[1] + red[2] + red[3]);
        __threadfence();
        float old = atomicAdd(&scal[4], 1.f);
        if (old == 63.f) {   // last block: all pg partials visible
            float pgs = atomicAdd(&scal[3], 0.f);
            float vfs = atomicAdd(&scal[2], 0.f);
            float ls = 0.f;
#pragma unroll
            for (int jj = 0; jj < AD; ++jj) ls += logstd[jj];
            float entropy = 0.5f + 0.5f * LOG2PI + ls / (float)AD;
            out[0] = pgs / (float)TH + VFC * (vfs / (float)TH) - ENTC * entropy;
        }
    }
}

extern "C" void kernel_launch(void* const* d_in, const int* in_sizes, int n_in,
                              void* d_out, int out_size, void* d_ws, size_t ws_size,
                              hipStream_t stream) {
    const float* s      = (const float*)d_in[0];
    const float* a      = (const float*)d_in[1];
    const float* r      = (const float*)d_in[2];
    const float* sp     = (const float*)d_in[3];
    const float* lpold  = (const float*)d_in[4];
    const float* dmask  = (const float*)d_in[5];
    const float* piW1   = (const float*)d_in[6];
    const float* pib1   = (const float*)d_in[7];
    const float* piW2   = (const float*)d_in[8];
    const float* pib2   = (const float*)d_in[9];
    const float* muW    = (const float*)d_in[10];
    const float* mub    = (const float*)d_in[11];
    const float* logstd = (const float*)d_in[12];
    const float* vW1    = (const float*)d_in[13];
    const float* vb1    = (const float*)d_in[14];
    const float* vW2    = (const float*)d_in[15];
    const float* vb2    = (const float*)d_in[16];
    const float* vhW    = (const float*)d_in[17];
    const float* vhb    = (const float*)d_in[18];

    float* ws      = (float*)d_ws;
    float* values  = ws + WS_VALUES;
    float* ratio   = ws + WS_RATIO;
    float* chunkP  = ws + WS_CHP;
    float* chunkB  = ws + WS_CHB;
    float* scal    = ws + WS_SCAL;
    unsigned short* bfbase = (unsigned short*)(ws + WS_BF);
    unsigned short* dPiW1 = bfbase + SW_PIW1;
    unsigned short* dPiW2 = bfbase + SW_PIW2;
    unsigned short* dVW1  = bfbase + SW_VW1;
    unsigned short* dVW2  = bfbase + SW_VW2;

    swizzle_kernel<<<192, 256, 0, stream>>>(piW1, vW1, piW2, vW2,
                                            dPiW1, dVW1, dPiW2, dVW2, scal);

    mlp_fused_kernel<<<TH / 64 + 1, 256, 0, stream>>>(
        s, sp + (size_t)(TH - 1) * SD,
        dPiW1, pib1, dPiW2, pib2, muW, mub, logstd, a, lpold,
        dVW1, vb1, dVW2, vb2, vhW, vhb,
        values, ratio);

    gae_fused_kernel<<<64, 256, 0, stream>>>(r, dmask, values, ratio, logstd,
                                             chunkP, chunkB, scal, (float*)d_out);
}

// Round 8
// 176.765 us; speedup vs baseline: 1.1830x; 1.0464x over previous
//
#include <hip/hip_runtime.h>
#include <math.h>

#define TH 65536
#define SD 128
#define AD 8
#define HD 256

constexpr float GAMMA  = 0.99f;
constexpr float LMBDA  = 0.95f;
constexpr float EPSC   = 0.2f;
constexpr float VFC    = 0.5f;
constexpr float ENTC   = 0.01f;
constexpr float LOG2PI = 1.8378770664093453f;

typedef _Float16 half8 __attribute__((ext_vector_type(8)));
typedef __fp16 fp16x2 __attribute__((ext_vector_type(2)));
typedef __attribute__((ext_vector_type(4))) float f32x4;

// workspace layout (float offsets)
constexpr size_t WS_VALUES = 0;        // TH+1 (reserve 65540)
constexpr size_t WS_RATIO  = 131080;   // TH
constexpr size_t WS_CHP    = 196616;   // 64
constexpr size_t WS_CHB    = 196680;   // 64
constexpr size_t WS_SCAL   = 196744;   // 8: [0]sum [1]sumsq [2]vf [3]pg [4]ticket [5]ctrA [6]ctrB
constexpr size_t WS_BF     = 196752;   // f16 weights (ushort offsets below)
constexpr size_t SW_PIW1 = 0;          // 32768
constexpr size_t SW_PIW2 = 32768;      // 65536
constexpr size_t SW_VW1  = 98304;      // 32768
constexpr size_t SW_VW2  = 131072;     // 65536 -> total 196608 ushorts

__device__ __forceinline__ unsigned pk2h(float a, float b) {
    fp16x2 h = __builtin_amdgcn_cvt_pkrtz(a, b);
    return __builtin_bit_cast(unsigned, h);
}

// fast tanh: clamp + exp + hw rcp
__device__ __forceinline__ float ftanh(float x) {
    float cx = fminf(fmaxf(x, -9.f), 9.f);
    float e = __expf(cx + cx);
    return (e - 1.f) * __builtin_amdgcn_rcpf(e + 1.f);
}

// ------------- weight swizzle: coalesced f32 reads, scattered 2B f16 stores
// dest frag layout (read as half8 by MFMA B): frag = (ks*16 + nt)*64 + kq*16 + nr,
// elem j = k&7, where ks=k>>5, kq=(k>>3)&3, nt=n>>4, nr=n&15.
__global__ __launch_bounds__(256) void swizzle_kernel(
    const float* __restrict__ piW1, const float* __restrict__ vW1,
    const float* __restrict__ piW2, const float* __restrict__ vW2,
    unsigned short* __restrict__ dPiW1, unsigned short* __restrict__ dVW1,
    unsigned short* __restrict__ dPiW2, unsigned short* __restrict__ dVW2,
    float* __restrict__ scal)
{
    if (blockIdx.x == 0 && threadIdx.x < 8) scal[threadIdx.x] = 0.f;
    int g = blockIdx.x * 256 + threadIdx.x;   // float4 id, 49152 total
    const float* S; unsigned short* D; int lo;
    if      (g <  8192) { S = piW1; D = dPiW1; lo = 0;     }
    else if (g < 24576) { S = piW2; D = dPiW2; lo = 8192;  }
    else if (g < 32768) { S = vW1;  D = dVW1;  lo = 24576; }
    else                { S = vW2;  D = dVW2;  lo = 32768; }
    int q = g - lo;
    int k = q >> 6, n4 = (q & 63) * 4;        // 4 consecutive n, same nt
    float4 v = *(const float4*)(S + (size_t)k * HD + n4);
    int ks = k >> 5, kq = (k >> 3) & 3, j = k & 7;
    int nt = n4 >> 4, nr = n4 & 15;
    unsigned short* base = D + ((size_t)(ks * 16 + nt) * 64 + kq * 16 + nr) * 8 + j;
    unsigned p01 = pk2h(v.x, v.y);
    unsigned p23 = pk2h(v.z, v.w);
    base[0]  = (unsigned short)(p01 & 0xffff);
    base[8]  = (unsigned short)(p01 >> 16);
    base[16] = (unsigned short)(p23 & 0xffff);
    base[24] = (unsigned short)(p23 >> 16);
}

// layer 1 for a 16x128 wave tile: A from registers, B from global
__device__ __forceinline__ void runlayer1(
    f32x4* acc, const unsigned short* __restrict__ Ws,
    const half8* afr, int colhalf, int lane)
{
#pragma unroll
    for (int nt = 0; nt < 8; ++nt) acc[nt] = (f32x4){0.f, 0.f, 0.f, 0.f};
#pragma unroll
    for (int ks = 0; ks < 4; ++ks) {
#pragma unroll
        for (int ntl = 0; ntl < 8; ++ntl) {
            half8 bf = ((const half8*)Ws)[(ks * 16 + colhalf * 8 + ntl) * 64 + lane];
            acc[ntl] = __builtin_amdgcn_mfma_f32_16x16x32_f16(afr[ks], bf, acc[ntl], 0, 0, 0);
        }
    }
}

// layer 2 for a 16x128 wave tile: A from h1 LDS (stride 264), B from global
__device__ __forceinline__ void runlayer2(
    f32x4* acc, const unsigned short* __restrict__ Ws,
    const unsigned short* h1, int l15, int quad, int rowgrp, int colhalf, int lane)
{
#pragma unroll
    for (int nt = 0; nt < 8; ++nt) acc[nt] = (f32x4){0.f, 0.f, 0.f, 0.f};
#pragma unroll
    for (int ks = 0; ks < 8; ++ks) {
        half8 af = *(const half8*)(h1 + (rowgrp * 16 + l15) * 264 + ks * 32 + quad * 8);
#pragma unroll
        for (int ntl = 0; ntl < 8; ++ntl) {
            half8 bf = ((const half8*)Ws)[(ks * 16 + colhalf * 8 + ntl) * 64 + lane];
            acc[ntl] = __builtin_amdgcn_mfma_f32_16x16x32_f16(af, bf, acc[ntl], 0, 0, 0);
        }
    }
}

// store 4 row-consecutive tanh outputs into LDS f16 (pk convert)
__device__ __forceinline__ void store4(unsigned short* dst, int stride,
                                       float t0, float t1, float t2, float t3)
{
    unsigned p01 = pk2h(t0, t1), p23 = pk2h(t2, t3);
    dst[0]          = (unsigned short)(p01 & 0xffff);
    dst[stride]     = (unsigned short)(p01 >> 16);
    dst[2 * stride] = (unsigned short)(p23 & 0xffff);
    dst[3 * stride] = (unsigned short)(p23 >> 16);
}

// ------------- fused pi+v MLP on 64-row tiles (4 rowgroups x 2 colhalves)
// layer-1 A-operand comes straight from global X into registers (no xs LDS)
__global__ __launch_bounds__(256, 4) void mlp_fused_kernel(
    const float* __restrict__ X, const float* __restrict__ Xlast,
    const unsigned short* __restrict__ piW1s, const float* __restrict__ pib1,
    const unsigned short* __restrict__ piW2s, const float* __restrict__ pib2,
    const float* __restrict__ muW, const float* __restrict__ mub,
    const float* __restrict__ logstd,
    const float* __restrict__ act, const float* __restrict__ lpold,
    const unsigned short* __restrict__ vW1s, const float* __restrict__ vb1,
    const unsigned short* __restrict__ vW2s, const float* __restrict__ vb2,
    const float* __restrict__ vhW, const float* __restrict__ vhb,
    float* __restrict__ values, float* __restrict__ ratio)
{
    __shared__ unsigned short h1[64 * 264];   // 33792 B
    __shared__ float cmb[64 * 8];             // 2048 B: mu accumulators (atomicAdd)
    __shared__ float val[64];                 // 256 B: value partial accumulators
    const int tid = threadIdx.x;
    const int lane = tid & 63, wave = tid >> 6;
    const int l15 = lane & 15, quad = lane >> 4;
    const int rowgrp = wave >> 1, colhalf = wave & 1;   // 4 x 2 over 64 rows
    const bool vonly = (blockIdx.x == gridDim.x - 1);
    const float* Xp = vonly ? Xlast : X + (size_t)blockIdx.x * 64 * SD;
    const int nrows = vonly ? 1 : 64;
    const int vout0 = vonly ? TH : blockIdx.x * 64;

    // zero the LDS accumulators (first use is after at least one later barrier)
    if (tid < 64) val[tid] = 0.f;
    cmb[tid] = 0.f; cmb[tid + 256] = 0.f;

    // layer-1 A fragments: row rowgrp*16+l15, cols ks*32+quad*8 .. +7 (f32 -> f16)
    const int rr = rowgrp * 16 + l15;
    const float* xrow = Xp + (size_t)(rr < nrows ? rr : 0) * SD;
    half8 afr[4];
#pragma unroll
    for (int ks = 0; ks < 4; ++ks) {
        float4 v0 = *(const float4*)(xrow + ks * 32 + quad * 8);
        float4 v1 = *(const float4*)(xrow + ks * 32 + quad * 8 + 4);
        if (rr >= nrows) { v0 = make_float4(0.f, 0.f, 0.f, 0.f); v1 = v0; }
        uint4 u = make_uint4(pk2h(v0.x, v0.y), pk2h(v0.z, v0.w),
                             pk2h(v1.x, v1.y), pk2h(v1.z, v1.w));
        afr[ks] = __builtin_bit_cast(half8, u);
    }

    f32x4 acc[8];

    if (!vonly) {
        // ---- pi layer 1 (A from regs)
        runlayer1(acc, piW1s, afr, colhalf, lane);
#pragma unroll
        for (int ntl = 0; ntl < 8; ++ntl) {
            int col = (colhalf * 8 + ntl) * 16 + l15;
            float bb = pib1[col];
            store4(&h1[(rowgrp * 16 + quad * 4) * 264 + col], 264,
                   ftanh(acc[ntl][0] + bb), ftanh(acc[ntl][1] + bb),
                   ftanh(acc[ntl][2] + bb), ftanh(acc[ntl][3] + bb));
        }
        __syncthreads();
        // ---- pi layer 2
        runlayer2(acc, piW2s, h1, l15, quad, rowgrp, colhalf, lane);
        // ---- mu head partials (fp32 VALU dot over this wave's 128 cols)
        float pm[4][8];
#pragma unroll
        for (int rg = 0; rg < 4; ++rg)
#pragma unroll
            for (int aj = 0; aj < 8; ++aj) pm[rg][aj] = 0.f;
#pragma unroll
        for (int ntl = 0; ntl < 8; ++ntl) {
            int col = (colhalf * 8 + ntl) * 16 + l15;
            float bb = pib2[col];
            float4 w0 = *(const float4*)(muW + (size_t)col * AD);
            float4 w1 = *(const float4*)(muW + (size_t)col * AD + 4);
            float wv[8] = {w0.x, w0.y, w0.z, w0.w, w1.x, w1.y, w1.z, w1.w};
#pragma unroll
            for (int rg = 0; rg < 4; ++rg) {
                float hv = ftanh(acc[ntl][rg] + bb);
#pragma unroll
                for (int aj = 0; aj < 8; ++aj) pm[rg][aj] = fmaf(hv, wv[aj], pm[rg][aj]);
            }
        }
#pragma unroll
        for (int off = 8; off >= 1; off >>= 1)
#pragma unroll
            for (int rg = 0; rg < 4; ++rg)
#pragma unroll
                for (int aj = 0; aj < 8; ++aj)
                    pm[rg][aj] += __shfl_xor(pm[rg][aj], off, 16);
        if (l15 == 0) {
#pragma unroll
            for (int rg = 0; rg < 4; ++rg) {
                int rowi = rowgrp * 16 + quad * 4 + rg;
#pragma unroll
                for (int aj = 0; aj < 8; ++aj)
                    atomicAdd(&cmb[rowi * 8 + aj], pm[rg][aj]);
            }
        }
        __syncthreads();
        // ---- per-row log-prob ratio (reads cmb only)
        if (tid < 64) {
            int row = blockIdx.x * 64 + tid;
            const float* ar = act + (size_t)row * AD;
            float lp = 0.f;
#pragma unroll
            for (int aj = 0; aj < 8; ++aj) {
                float ls = logstd[aj];
                float mu = cmb[tid * 8 + aj] + mub[aj];
                float z = (ar[aj] - mu) * __expf(-ls);
                lp += -0.5f * z * z - ls;
            }
            lp -= 4.f * LOG2PI;
            ratio[row] = __expf(lp - lpold[row]);
        }
        __syncthreads();    // h1 reads (pi layer 2) done before v layer 1 overwrites
    }

    // ---- v layer 1 (A frags still in registers)
    runlayer1(acc, vW1s, afr, colhalf, lane);
#pragma unroll
    for (int ntl = 0; ntl < 8; ++ntl) {
        int col = (colhalf * 8 + ntl) * 16 + l15;
        float bb = vb1[col];
        store4(&h1[(rowgrp * 16 + quad * 4) * 264 + col], 264,
               ftanh(acc[ntl][0] + bb), ftanh(acc[ntl][1] + bb),
               ftanh(acc[ntl][2] + bb), ftanh(acc[ntl][3] + bb));
    }
    __syncthreads();
    // ---- v layer 2 + value head
    runlayer2(acc, vW2s, h1, l15, quad, rowgrp, colhalf, lane);
    float vp[4] = {0.f, 0.f, 0.f, 0.f};
#pragma unroll
    for (int ntl = 0; ntl < 8; ++ntl) {
        int col = (colhalf * 8 + ntl) * 16 + l15;
        float bb = vb2[col], w = vhW[col];
#pragma unroll
        for (int rg = 0; rg < 4; ++rg) vp[rg] += ftanh(acc[ntl][rg] + bb) * w;
    }
#pragma unroll
    for (int off = 8; off >= 1; off >>= 1)
#pragma unroll
        for (int rg = 0; rg < 4; ++rg) vp[rg] += __shfl_xor(vp[rg], off, 16);
    if (l15 == 0) {
#pragma unroll
        for (int rg = 0; rg < 4; ++rg)
            atomicAdd(&val[rowgrp * 16 + quad * 4 + rg], vp[rg]);
    }
    __syncthreads();
    if (tid < nrows)
        values[vout0 + tid] = val[tid] + vhb[0];
}

// ------------- single fused GAE + PG kernel (64 co-resident blocks, atomic phases)
__global__ __launch_bounds__(256) void gae_fused_kernel(
    const float* __restrict__ rw, const float* __restrict__ m,
    const float* __restrict__ values, const float* __restrict__ ratio,
    const float* __restrict__ logstd,
    float* __restrict__ chunkP, float* __restrict__ chunkB,
    float* __restrict__ scal, float* __restrict__ out)
{
    __shared__ float sp_[256], sb_[256];
    __shared__ float cp[64], cb[64];
    __shared__ float red[12];
    __shared__ float bcast[4];
    const int j = threadIdx.x;
    const int t0 = blockIdx.x * 1024 + j * 4;
    const float g = GAMMA * LMBDA;

    // --- phase A: local deltas + block suffix scan of affine maps
    float4 vv = *(const float4*)(values + t0);
    float v4 = values[t0 + 4];
    float4 rr = *(const float4*)(rw + t0);
    float4 mm = *(const float4*)(m + t0);
    float vs[5] = {vv.x, vv.y, vv.z, vv.w, v4};
    float rs[4] = {rr.x, rr.y, rr.z, rr.w};
    float ms[4] = {mm.x, mm.y, mm.z, mm.w};
    float ds[4];
#pragma unroll
    for (int i = 0; i < 4; ++i)
        ds[i] = rs[i] + GAMMA * vs[i + 1] * ms[i] - vs[i];

    float P = 1.f, B = 0.f;
#pragma unroll
    for (int i = 3; i >= 0; --i) {
        float p = g * ms[i];
        B = ds[i] + p * B;
        P = p * P;
    }
    sp_[j] = P; sb_[j] = B;
    __syncthreads();
    for (int dstep = 1; dstep < 256; dstep <<= 1) {
        float pj = sp_[j], bj = sb_[j], pk = 1.f, bk = 0.f;
        if (j + dstep < 256) { pk = sp_[j + dstep]; bk = sb_[j + dstep]; }
        __syncthreads();
        sp_[j] = pj * pk;
        sb_[j] = bj + pj * bk;
        __syncthreads();
    }
    if (j == 0) {
        atomicExch(&chunkP[blockIdx.x], sp_[0]);
        atomicExch(&chunkB[blockIdx.x], sb_[0]);
        __threadfence();
        atomicAdd(&scal[5], 1.f);
        while (atomicAdd(&scal[5], 0.f) < 64.f) __builtin_amdgcn_s_sleep(2);
    }
    __syncthreads();
    // --- phase B: parallel fetch of all chunk (P,B), serial compose in LDS
    if (j < 64) {
        cp[j] = atomicAdd(&chunkP[j], 0.f);
        cb[j] = atomicAdd(&chunkB[j], 0.f);
    }
    __syncthreads();
    if (j == 0) {
        float A = 0.f;
        for (int c = 63; c > (int)blockIdx.x; --c) A = cb[c] + cp[c] * A;
        bcast[0] = A;
    }
    __syncthreads();
    const float carry = bcast[0];

    // --- phase C: apply carry, advantages in regs, sum/sumsq/huber reductions
    float Pe = 1.f, Be = 0.f;
    if (j < 255) { Pe = sp_[j + 1]; Be = sb_[j + 1]; }
    float A = Be + Pe * carry;
    float s1 = 0.f, s2 = 0.f, vf = 0.f;
    float a4[4];
#pragma unroll
    for (int i = 3; i >= 0; --i) {
        A = ds[i] + g * ms[i] * A;
        a4[i] = A;
        float ab = fabsf(A);
        vf += (ab < 1.f) ? 0.5f * A * A : ab - 0.5f;   // huber(v-ret) == huber(adv)
        s1 += A;
        s2 += A * A;
    }
#pragma unroll
    for (int off = 32; off >= 1; off >>= 1) {
        s1 += __shfl_down(s1, off, 64);
        s2 += __shfl_down(s2, off, 64);
        vf += __shfl_down(vf, off, 64);
    }
    if ((j & 63) == 0) {
        int w = j >> 6;
        red[w] = s1; red[4 + w] = s2; red[8 + w] = vf;
    }
    __syncthreads();
    if (j == 0) {
        atomicAdd(&scal[0], red[0] + red[1] + red[2] + red[3]);
        atomicAdd(&scal[1], red[4] + red[5] + red[6] + red[7]);
        atomicAdd(&scal[2], red[8] + red[9] + red[10] + red[11]);
        __threadfence();
        atomicAdd(&scal[6], 1.f);
        while (atomicAdd(&scal[6], 0.f) < 64.f) __builtin_amdgcn_s_sleep(2);
        bcast[1] = atomicAdd(&scal[0], 0.f);
        bcast[2] = atomicAdd(&scal[1], 0.f);
    }
    __syncthreads();

    // --- phase D: normalize + clipped PG over in-register advantages
    const float ssum = bcast[1], ssq = bcast[2];
    const float meanA = ssum / (float)TH;
    const float varA = fmaxf((ssq - ssum * ssum / (float)TH) / (float)(TH - 1), 0.f);
    const float inv = 1.f / (sqrtf(varA) + 1e-8f);

    float4 r4 = *(const float4*)(ratio + t0);
    float rt[4] = {r4.x, r4.y, r4.z, r4.w};
    float pg = 0.f;
#pragma unroll
    for (int i = 0; i < 4; ++i) {
        float aN = (a4[i] - meanA) * inv;
        float rc = fminf(fmaxf(rt[i], 1.f - EPSC), 1.f + EPSC);
        pg -= fminf(rt[i] * aN, rc * aN);
    }
#pragma unroll
    for (int off = 32; off >= 1; off >>= 1) pg += __shfl_down(pg, off, 64);
    if ((j & 63) == 0) red[j >> 6] = pg;
    __syncthreads();
    if (j == 0) {
        atomicAdd(&scal[3], red[0] + red[1] + red[2] + red[3]);
        __threadfence();
        float old = atomicAdd(&scal[4], 1.f);
        if (old == 63.f) {   // last block: all pg partials visible
            float pgs = atomicAdd(&scal[3], 0.f);
            float vfs = atomicAdd(&scal[2], 0.f);
            float ls = 0.f;
#pragma unroll
            for (int jj = 0; jj < AD; ++jj) ls += logstd[jj];
            float entropy = 0.5f + 0.5f * LOG2PI + ls / (float)AD;
            out[0] = pgs / (float)TH + VFC * (vfs / (float)TH) - ENTC * entropy;
        }
    }
}

extern "C" void kernel_launch(void* const* d_in, const int* in_sizes, int n_in,
                              void* d_out, int out_size, void* d_ws, size_t ws_size,
                              hipStream_t stream) {
    const float* s      = (const float*)d_in[0];
    const float* a      = (const float*)d_in[1];
    const float* r      = (const float*)d_in[2];
    const float* sp     = (const float*)d_in[3];
    const float* lpold  = (const float*)d_in[4];
    const float* dmask  = (const float*)d_in[5];
    const float* piW1   = (const float*)d_in[6];
    const float* pib1   = (const float*)d_in[7];
    const float* piW2   = (const float*)d_in[8];
    const float* pib2   = (const float*)d_in[9];
    const float* muW    = (const float*)d_in[10];
    const float* mub    = (const float*)d_in[11];
    const float* logstd = (const float*)d_in[12];
    const float* vW1    = (const float*)d_in[13];
    const float* vb1    = (const float*)d_in[14];
    const float* vW2    = (const float*)d_in[15];
    const float* vb2    = (const float*)d_in[16];
    const float* vhW    = (const float*)d_in[17];
    const float* vhb    = (const float*)d_in[18];

    float* ws      = (float*)d_ws;
    float* values  = ws + WS_VALUES;
    float* ratio   = ws + WS_RATIO;
    float* chunkP  = ws + WS_CHP;
    float* chunkB  = ws + WS_CHB;
    float* scal    = ws + WS_SCAL;
    unsigned short* bfbase = (unsigned short*)(ws + WS_BF);
    unsigned short* dPiW1 = bfbase + SW_PIW1;
    unsigned short* dPiW2 = bfbase + SW_PIW2;
    unsigned short* dVW1  = bfbase + SW_VW1;
    unsigned short* dVW2  = bfbase + SW_VW2;

    swizzle_kernel<<<192, 256, 0, stream>>>(piW1, vW1, piW2, vW2,
                                            dPiW1, dVW1, dPiW2, dVW2, scal);

    mlp_fused_kernel<<<TH / 64 + 1, 256, 0, stream>>>(
        s, sp + (size_t)(TH - 1) * SD,
        dPiW1, pib1, dPiW2, pib2, muW, mub, logstd, a, lpold,
        dVW1, vb1, dVW2, vb2, vhW, vhb,
        values, ratio);

    gae_fused_kernel<<<64, 256, 0, stream>>>(r, dmask, values, ratio, logstd,
                                             chunkP, chunkB, scal, (float*)d_out);
}